// Round 4
// baseline (182.621 us; speedup 1.0000x reference)
//
#include <hip/hip_runtime.h>
#include <hip/hip_bf16.h>

#define GRID_D 128
#define NSITES (GRID_D * GRID_D)   // 16384
#define HID 64
#define BATCH 64

#define WPB 4                       // waves per block
#define BLOCKS 2048
#define BLOCKS_PER_BATCH (BLOCKS / BATCH)       // 32
#define WAVES_TOTAL (BLOCKS * WPB)              // 8192
#define WAVES_PER_BATCH (WAVES_TOTAL / BATCH)   // 128
#define TILES_PER_WAVE (NSITES / (WAVES_PER_BATCH * 16))  // 8

typedef short bf16x8 __attribute__((ext_vector_type(8)));
typedef float f32x4  __attribute__((ext_vector_type(4)));

__device__ __forceinline__ unsigned short f2bf(float f) {
    return __builtin_bit_cast(unsigned short, __float2bfloat16(f));
}

// Per 16-site tile: lane l serves site l%16; k-group (l>>4) covers k=(l>>4)*8..+7
// of each K=32 step. Hidden layer = 8 MFMAs (2 K-steps x 4 N-tiles of 16).
// Output is a full site-sum -> C consumed as sum(relu(C[:,n])*W_post[n]),
// no transpose, no LDS, no atomics (block partial -> d_ws, kernel2 reduces).
__global__ __launch_bounds__(256, 4)
void gauge_mfma(const float* __restrict__ x,
                const float* __restrict__ H,
                const float* __restrict__ W_emb,
                const float* __restrict__ b_emb,
                const float* __restrict__ W_hid,
                const float* __restrict__ b_hid,
                const float* __restrict__ W_post,
                float* __restrict__ ws)
{
    const int tid   = threadIdx.x;
    const int lane  = tid & 63;
    const int widx  = tid >> 6;
    const int wgid  = blockIdx.x * WPB + widx;
    const int b     = wgid / WAVES_PER_BATCH;
    const int wslot = wgid % WAVES_PER_BATCH;

    const int ls = lane & 15;         // site-in-tile (A row) == n-in-tile (B/C col)
    const int kl = (lane >> 4) * 8;   // k-chunk base within a K=32 step

    const float h00 = H[0], h01 = H[1], h10 = H[2], h11 = H[3];

    // ---- loop-invariant B fragments: B[k][n] = W_hid[k*64+n], k=s*32+kl+i, n=t*16+ls
    bf16x8 bfrag[4][2];
    #pragma unroll
    for (int t = 0; t < 4; ++t) {
        #pragma unroll
        for (int s = 0; s < 2; ++s) {
            union { bf16x8 v; unsigned short us[8]; } r;
            #pragma unroll
            for (int i = 0; i < 8; ++i)
                r.us[i] = f2bf(W_hid[(s * 32 + kl + i) * HID + t * 16 + ls]);
            bfrag[t][s] = r.v;
        }
    }

    // per-lane bias / post-weight for each N-tile (col = t*16+ls)
    float bh[4], wp[4];
    #pragma unroll
    for (int t = 0; t < 4; ++t) {
        bh[t] = b_hid[t * 16 + ls];
        wp[t] = W_post[t * 16 + ls];
    }

    // hoist loop-invariant b_emb slices (k = s*32+kl+i)
    float be[2][8];
    #pragma unroll
    for (int s = 0; s < 2; ++s) {
        const float4 v0 = *(const float4*)(b_emb + s * 32 + kl);
        const float4 v1 = *(const float4*)(b_emb + s * 32 + kl + 4);
        be[s][0] = v0.x; be[s][1] = v0.y; be[s][2] = v0.z; be[s][3] = v0.w;
        be[s][4] = v1.x; be[s][5] = v1.y; be[s][6] = v1.z; be[s][7] = v1.w;
    }

    const float* __restrict__ xb = x + (size_t)b * NSITES * 2;
    float o = 0.0f;

    #pragma unroll 2
    for (int tile = 0; tile < TILES_PER_WAVE; ++tile) {
        const int site = wslot * (16 * TILES_PER_WAVE) + tile * 16 + ls;
        const int xc = site & (GRID_D - 1);
        const int yc = site >> 7;
        const int n0 = xc + (((yc + 1) & (GRID_D - 1)) << 7);
        const int n1 = xc + (((yc - 1) & (GRID_D - 1)) << 7);
        const int n2 = ((xc - 1) & (GRID_D - 1)) + (yc << 7);
        const int n3 = ((xc + 1) & (GRID_D - 1)) + (yc << 7);

        const float2 xi = *(const float2*)(xb + 2 * site);
        const float2 xu = *(const float2*)(xb + 2 * n0);
        const float2 xd = *(const float2*)(xb + 2 * n1);
        const float2 xl = *(const float2*)(xb + 2 * n2);
        const float2 xr = *(const float2*)(xb + 2 * n3);

        const float s0 = xi.x * fmaf(h00, xu.x, h01 * xu.y) + xi.y * fmaf(h10, xu.x, h11 * xu.y);
        const float s1 = xi.x * fmaf(h00, xd.x, h01 * xd.y) + xi.y * fmaf(h10, xd.x, h11 * xd.y);
        const float s2 = xi.x * fmaf(h00, xl.x, h01 * xl.y) + xi.y * fmaf(h10, xl.x, h11 * xl.y);
        const float s3 = xi.x * fmaf(h00, xr.x, h01 * xr.y) + xi.y * fmaf(h10, xr.x, h11 * xr.y);

        // ---- A fragments: h1[k] = relu(b_emb[k] + sum_m s_m * W_emb[m][k]), k = s*32+kl+i
        bf16x8 afrag[2];
        #pragma unroll
        for (int s = 0; s < 2; ++s) {
            const int kb = s * 32 + kl;
            float hv[8];
            #pragma unroll
            for (int i = 0; i < 8; ++i) hv[i] = be[s][i];
            #pragma unroll
            for (int m = 0; m < 4; ++m) {
                const float sm = (m == 0) ? s0 : (m == 1) ? s1 : (m == 2) ? s2 : s3;
                const float4 w0 = *(const float4*)(W_emb + m * HID + kb);
                const float4 w1 = *(const float4*)(W_emb + m * HID + kb + 4);
                hv[0] = fmaf(sm, w0.x, hv[0]); hv[1] = fmaf(sm, w0.y, hv[1]);
                hv[2] = fmaf(sm, w0.z, hv[2]); hv[3] = fmaf(sm, w0.w, hv[3]);
                hv[4] = fmaf(sm, w1.x, hv[4]); hv[5] = fmaf(sm, w1.y, hv[5]);
                hv[6] = fmaf(sm, w1.z, hv[6]); hv[7] = fmaf(sm, w1.w, hv[7]);
            }
            union { bf16x8 v; unsigned short us[8]; } r;
            #pragma unroll
            for (int i = 0; i < 8; ++i)
                r.us[i] = f2bf(fmaxf(hv[i], 0.0f));
            afrag[s] = r.v;
        }

        // ---- hidden layer via MFMA + fused relu/post epilogue
        #pragma unroll
        for (int t = 0; t < 4; ++t) {
            f32x4 acc = { bh[t], bh[t], bh[t], bh[t] };   // bias init
            acc = __builtin_amdgcn_mfma_f32_16x16x32_bf16(afrag[0], bfrag[t][0], acc, 0, 0, 0);
            acc = __builtin_amdgcn_mfma_f32_16x16x32_bf16(afrag[1], bfrag[t][1], acc, 0, 0, 0);
            #pragma unroll
            for (int r = 0; r < 4; ++r)
                o = fmaf(fmaxf(acc[r], 0.0f), wp[t], o);
        }
    }

    // wave reduce, block reduce, one plain store per block (no atomics)
    #pragma unroll
    for (int off = 32; off > 0; off >>= 1)
        o += __shfl_down(o, off, 64);

    __shared__ float part[WPB];
    if (lane == 0) part[widx] = o;
    __syncthreads();
    if (tid == 0)
        ws[blockIdx.x] = part[0] + part[1] + part[2] + part[3];
}

// 64 threads: out[b] = sum of this batch's 32 block partials + N*b_post
__global__ __launch_bounds__(64)
void gauge_reduce(const float* __restrict__ ws,
                  const float* __restrict__ b_post,
                  float* __restrict__ out)
{
    const int b = threadIdx.x;
    float t = (float)NSITES * b_post[0];
    #pragma unroll
    for (int j = 0; j < BLOCKS_PER_BATCH; ++j)
        t += ws[b * BLOCKS_PER_BATCH + j];
    out[b] = t;
}

extern "C" void kernel_launch(void* const* d_in, const int* in_sizes, int n_in,
                              void* d_out, int out_size, void* d_ws, size_t ws_size,
                              hipStream_t stream)
{
    const float* x      = (const float*)d_in[0];
    const float* H      = (const float*)d_in[1];
    const float* W_emb  = (const float*)d_in[2];
    const float* b_emb  = (const float*)d_in[3];
    const float* W_hid  = (const float*)d_in[4];
    const float* b_hid  = (const float*)d_in[5];
    const float* W_post = (const float*)d_in[6];
    const float* b_post = (const float*)d_in[7];
    float* out = (float*)d_out;
    float* ws  = (float*)d_ws;   // 2048 floats of scratch

    gauge_mfma<<<dim3(BLOCKS), dim3(256), 0, stream>>>(
        x, H, W_emb, b_emb, W_hid, b_hid, W_post, ws);
    gauge_reduce<<<dim3(1), dim3(64), 0, stream>>>(ws, b_post, out);
}

// Round 7
// 99.440 us; speedup vs baseline: 1.8365x; 1.8365x over previous
//
#include <hip/hip_runtime.h>
#include <hip/hip_bf16.h>

#define GRID_D 128
#define NSITES (GRID_D * GRID_D)   // 16384
#define HID 64
#define BATCH 64

#define WPB 4                       // waves per block
#define BLOCKS 2048
#define BLOCKS_PER_BATCH (BLOCKS / BATCH)       // 32
#define WAVES_TOTAL (BLOCKS * WPB)              // 8192
#define WAVES_PER_BATCH (WAVES_TOTAL / BATCH)   // 128
#define TILES_PER_WAVE (NSITES / (WAVES_PER_BATCH * 16))  // 8

typedef short bf16x8 __attribute__((ext_vector_type(8)));
typedef float f32x4  __attribute__((ext_vector_type(4)));

__device__ __forceinline__ unsigned short f2bf(float f) {
    return __builtin_bit_cast(unsigned short, __float2bfloat16(f));
}

// Per 16-site tile: lane l serves site l%16; k-group (l>>4) covers k=(l>>4)*8..+7
// of each K=32 step. Hidden layer = 8 MFMAs (2 K-steps x 4 N-tiles of 16).
// Output is a full site-sum -> C consumed as sum(relu(C[:,n])*W_post[n]),
// no transpose, no LDS, no atomics (block partial -> d_ws, kernel2 reduces).
// NOTE: no min-waves launch bound and no tile-loop unroll -- R4 showed that
// combo spills bfrag (240MB scratch fetch, 2x slowdown).
__global__ __launch_bounds__(256)
void gauge_mfma(const float* __restrict__ x,
                const float* __restrict__ H,
                const float* __restrict__ W_emb,
                const float* __restrict__ b_emb,
                const float* __restrict__ W_hid,
                const float* __restrict__ b_hid,
                const float* __restrict__ W_post,
                float* __restrict__ ws)
{
    const int tid   = threadIdx.x;
    const int lane  = tid & 63;
    const int widx  = tid >> 6;
    const int wgid  = blockIdx.x * WPB + widx;
    const int b     = wgid / WAVES_PER_BATCH;
    const int wslot = wgid % WAVES_PER_BATCH;

    const int ls = lane & 15;         // site-in-tile (A row) == n-in-tile (B/C col)
    const int kl = (lane >> 4) * 8;   // k-chunk base within a K=32 step

    const float h00 = H[0], h01 = H[1], h10 = H[2], h11 = H[3];

    // ---- loop-invariant B fragments: B[k][n] = W_hid[k*64+n], k=s*32+kl+i, n=t*16+ls
    bf16x8 bfrag[4][2];
    #pragma unroll
    for (int t = 0; t < 4; ++t) {
        #pragma unroll
        for (int s = 0; s < 2; ++s) {
            union { bf16x8 v; unsigned short us[8]; } r;
            #pragma unroll
            for (int i = 0; i < 8; ++i)
                r.us[i] = f2bf(W_hid[(s * 32 + kl + i) * HID + t * 16 + ls]);
            bfrag[t][s] = r.v;
        }
    }

    // per-lane bias / post-weight for each N-tile (col = t*16+ls)
    float bh[4], wp[4];
    #pragma unroll
    for (int t = 0; t < 4; ++t) {
        bh[t] = b_hid[t * 16 + ls];
        wp[t] = W_post[t * 16 + ls];
    }

    // hoist loop-invariant b_emb slices (k = s*32+kl+i)
    float be[2][8];
    #pragma unroll
    for (int s = 0; s < 2; ++s) {
        const float4 v0 = *(const float4*)(b_emb + s * 32 + kl);
        const float4 v1 = *(const float4*)(b_emb + s * 32 + kl + 4);
        be[s][0] = v0.x; be[s][1] = v0.y; be[s][2] = v0.z; be[s][3] = v0.w;
        be[s][4] = v1.x; be[s][5] = v1.y; be[s][6] = v1.z; be[s][7] = v1.w;
    }

    const float* __restrict__ xb = x + (size_t)b * NSITES * 2;
    float o = 0.0f;

    for (int tile = 0; tile < TILES_PER_WAVE; ++tile) {
        const int site = wslot * (16 * TILES_PER_WAVE) + tile * 16 + ls;
        const int xc = site & (GRID_D - 1);
        const int yc = site >> 7;
        const int n0 = xc + (((yc + 1) & (GRID_D - 1)) << 7);
        const int n1 = xc + (((yc - 1) & (GRID_D - 1)) << 7);
        const int n2 = ((xc - 1) & (GRID_D - 1)) + (yc << 7);
        const int n3 = ((xc + 1) & (GRID_D - 1)) + (yc << 7);

        const float2 xi = *(const float2*)(xb + 2 * site);
        const float2 xu = *(const float2*)(xb + 2 * n0);
        const float2 xd = *(const float2*)(xb + 2 * n1);
        const float2 xl = *(const float2*)(xb + 2 * n2);
        const float2 xr = *(const float2*)(xb + 2 * n3);

        const float s0 = xi.x * fmaf(h00, xu.x, h01 * xu.y) + xi.y * fmaf(h10, xu.x, h11 * xu.y);
        const float s1 = xi.x * fmaf(h00, xd.x, h01 * xd.y) + xi.y * fmaf(h10, xd.x, h11 * xd.y);
        const float s2 = xi.x * fmaf(h00, xl.x, h01 * xl.y) + xi.y * fmaf(h10, xl.x, h11 * xl.y);
        const float s3 = xi.x * fmaf(h00, xr.x, h01 * xr.y) + xi.y * fmaf(h10, xr.x, h11 * xr.y);

        // ---- A fragments: h1[k] = relu(b_emb[k] + sum_m s_m * W_emb[m][k]), k = s*32+kl+i
        bf16x8 afrag[2];
        #pragma unroll
        for (int s = 0; s < 2; ++s) {
            const int kb = s * 32 + kl;
            float hv[8];
            #pragma unroll
            for (int i = 0; i < 8; ++i) hv[i] = be[s][i];
            #pragma unroll
            for (int m = 0; m < 4; ++m) {
                const float sm = (m == 0) ? s0 : (m == 1) ? s1 : (m == 2) ? s2 : s3;
                const float4 w0 = *(const float4*)(W_emb + m * HID + kb);
                const float4 w1 = *(const float4*)(W_emb + m * HID + kb + 4);
                hv[0] = fmaf(sm, w0.x, hv[0]); hv[1] = fmaf(sm, w0.y, hv[1]);
                hv[2] = fmaf(sm, w0.z, hv[2]); hv[3] = fmaf(sm, w0.w, hv[3]);
                hv[4] = fmaf(sm, w1.x, hv[4]); hv[5] = fmaf(sm, w1.y, hv[5]);
                hv[6] = fmaf(sm, w1.z, hv[6]); hv[7] = fmaf(sm, w1.w, hv[7]);
            }
            union { bf16x8 v; unsigned short us[8]; } r;
            #pragma unroll
            for (int i = 0; i < 8; ++i)
                r.us[i] = f2bf(fmaxf(hv[i], 0.0f));
            afrag[s] = r.v;
        }

        // ---- hidden layer via MFMA + fused relu/post epilogue
        #pragma unroll
        for (int t = 0; t < 4; ++t) {
            f32x4 acc = { bh[t], bh[t], bh[t], bh[t] };   // bias init
            acc = __builtin_amdgcn_mfma_f32_16x16x32_bf16(afrag[0], bfrag[t][0], acc, 0, 0, 0);
            acc = __builtin_amdgcn_mfma_f32_16x16x32_bf16(afrag[1], bfrag[t][1], acc, 0, 0, 0);
            #pragma unroll
            for (int r = 0; r < 4; ++r)
                o = fmaf(fmaxf(acc[r], 0.0f), wp[t], o);
        }
    }

    // wave reduce, block reduce, one plain store per block (no atomics)
    #pragma unroll
    for (int off = 32; off > 0; off >>= 1)
        o += __shfl_down(o, off, 64);

    __shared__ float part[WPB];
    if (lane == 0) part[widx] = o;
    __syncthreads();
    if (tid == 0)
        ws[blockIdx.x] = part[0] + part[1] + part[2] + part[3];
}

// 64 threads: out[b] = sum of this batch's 32 block partials + N*b_post
__global__ __launch_bounds__(64)
void gauge_reduce(const float* __restrict__ ws,
                  const float* __restrict__ b_post,
                  float* __restrict__ out)
{
    const int b = threadIdx.x;
    float t = (float)NSITES * b_post[0];
    #pragma unroll
    for (int j = 0; j < BLOCKS_PER_BATCH; ++j)
        t += ws[b * BLOCKS_PER_BATCH + j];
    out[b] = t;
}

extern "C" void kernel_launch(void* const* d_in, const int* in_sizes, int n_in,
                              void* d_out, int out_size, void* d_ws, size_t ws_size,
                              hipStream_t stream)
{
    const float* x      = (const float*)d_in[0];
    const float* H      = (const float*)d_in[1];
    const float* W_emb  = (const float*)d_in[2];
    const float* b_emb  = (const float*)d_in[3];
    const float* W_hid  = (const float*)d_in[4];
    const float* b_hid  = (const float*)d_in[5];
    const float* W_post = (const float*)d_in[6];
    const float* b_post = (const float*)d_in[7];
    float* out = (float*)d_out;
    float* ws  = (float*)d_ws;   // 2048 floats of scratch

    gauge_mfma<<<dim3(BLOCKS), dim3(256), 0, stream>>>(
        x, H, W_emb, b_emb, W_hid, b_hid, W_post, ws);
    gauge_reduce<<<dim3(1), dim3(64), 0, stream>>>(ws, b_post, out);
}